// Round 7
// baseline (389.485 us; speedup 1.0000x reference)
//
#include <hip/hip_runtime.h>

#define B2 2
#define DEG 16
#define SLOPE 0.2f

typedef __attribute__((ext_vector_type(8))) short short8;
typedef __attribute__((ext_vector_type(8))) unsigned short ushort8;
typedef __attribute__((ext_vector_type(4))) unsigned short ushort4v;
typedef __attribute__((ext_vector_type(4))) float f32x4;

__device__ inline unsigned short f2bf(float f) {
  union { float f; unsigned u; } v; v.f = f;
  unsigned r = v.u + 0x7fff + ((v.u >> 16) & 1);   // RNE
  return (unsigned short)(r >> 16);
}
__device__ inline float bf2f(unsigned short u) {
  union { unsigned u; float f; } c; c.u = ((unsigned)u) << 16;
  return c.f;
}

// Device-scope generation barrier. Safe across XCDs (agent-scope atomics).
// Requires all gridDim.x blocks co-resident (guaranteed: launch_bounds(256,2)
// => VGPR<=256 => >=2 waves/SIMD => 2 blocks/CU; LDS 36.9KB*2 <= 160KB;
// grid=512 on 256 CUs).
__device__ inline void grid_barrier(unsigned* bar, unsigned G) {
  __syncthreads();
  if (threadIdx.x == 0) {
    unsigned gen = __hip_atomic_load(&bar[1], __ATOMIC_RELAXED, __HIP_MEMORY_SCOPE_AGENT);
    unsigned arr = __hip_atomic_fetch_add(&bar[0], 1u, __ATOMIC_ACQ_REL, __HIP_MEMORY_SCOPE_AGENT);
    if (arr == G - 1) {
      __hip_atomic_store(&bar[0], 0u, __ATOMIC_RELAXED, __HIP_MEMORY_SCOPE_AGENT);
      __hip_atomic_store(&bar[1], gen + 1u, __ATOMIC_RELEASE, __HIP_MEMORY_SCOPE_AGENT);
    } else {
      while (__hip_atomic_load(&bar[1], __ATOMIC_ACQUIRE, __HIP_MEMORY_SCOPE_AGENT) == gen)
        __builtin_amdgcn_s_sleep(2);
    }
  }
  __syncthreads();
}

__device__ inline float wave_dot256(const float* __restrict__ a,
                                    const float* __restrict__ b, int lane) {
  float4 x = *(const float4*)(a + lane * 4);
  float4 y = *(const float4*)(b + lane * 4);
  float v = x.x * y.x + x.y * y.y + x.z * y.z + x.w * y.w;
  #pragma unroll
  for (int off = 32; off; off >>= 1) v += __shfl_down(v, off);
  return v;
}

__global__ __launch_bounds__(256, 2) void fused_k(
    const float* __restrict__ nodes,
    const float* __restrict__ Ws, const float* __restrict__ bs,
    const float* __restrict__ Wt, const float* __restrict__ bt,
    const float* __restrict__ Wv, const float* __restrict__ bv,
    const float* __restrict__ Wa, const float* __restrict__ ba,
    const int* __restrict__ usrc, const int* __restrict__ utgt,
    const int* __restrict__ tid_arr,
    unsigned short* __restrict__ WsT, unsigned short* __restrict__ WvT,
    unsigned short* __restrict__ nodes_bf,
    float* __restrict__ ws_comb, float* __restrict__ wt_comb,
    float* __restrict__ consts,
    float* __restrict__ an_s, float* __restrict__ an_t,
    float* __restrict__ alpha, unsigned short* __restrict__ vals_bf,
    float* __restrict__ out, unsigned* __restrict__ bar,
    int nrows, int Ms, int Mt, int Ns) {
  constexpr int LDT = 72;
  __shared__ unsigned short As[128 * LDT];
  __shared__ unsigned short Bs[128 * LDT];
  const unsigned G = gridDim.x;
  const int bid = blockIdx.x;
  const int t = threadIdx.x;
  const int lane = t & 63;
  const int widx = t >> 6;

  // ---- P1: combined attention weights (514 wave-tasks over 129 vblocks) ----
  for (int vb = bid; vb < 129; vb += G) {
    int wave = vb * 4 + widx;
    if (wave < 514) {
      const float *vec, *wa;
      float* dst;
      if (wave < 256)       { vec = Ws + (long)wave * 256;         wa = Wa;       dst = ws_comb + wave; }
      else if (wave < 512)  { vec = Wt + (long)(wave - 256) * 256; wa = Wa + 256; dst = wt_comb + (wave - 256); }
      else if (wave == 512) { vec = bs; wa = Wa;       dst = consts; }
      else                  { vec = bt; wa = Wa + 256; dst = consts + 1; }
      float v = wave_dot256(vec, wa, lane);
      if (lane == 0) *dst = v;
    }
  }
  grid_barrier(bar, G);

  // ---- P2: vblocks 0..31 transpose Ws/Wv -> bf16 [N][K]; rest: nodes ->
  // bf16 + per-row logits (reads P1 combs) ----
  int nb2 = 32 + (nrows + 3) / 4;
  for (int vb = bid; vb < nb2; vb += G) {
    if (vb < 32) {
      const float* src = (vb & 16) ? Wv : Ws;
      unsigned short* dst = (vb & 16) ? WvT : WsT;
      int rc = vb & 15;
      int r0 = (rc >> 2) * 64, c0 = (rc & 3) * 64;
      float (*tile)[65] = (float (*)[65])As;   // overlay on GEMM LDS
      int tr = t >> 6, tc = t & 63;
      __syncthreads();
      #pragma unroll
      for (int i = 0; i < 16; ++i) {
        int r = tr * 16 + i;
        tile[r][tc] = src[(long)(r0 + r) * 256 + c0 + tc];
      }
      __syncthreads();
      #pragma unroll
      for (int i = 0; i < 16; ++i) {
        int r = tr * 16 + i;
        dst[(long)(c0 + r) * 256 + r0 + tc] = f2bf(tile[tc][r]);
      }
    } else {
      int wave = (vb - 32) * 4 + widx;
      if (wave < nrows) {
        const float4 a = *(const float4*)(nodes + (long)wave * 256 + lane * 4);
        ushort4v p;
        p[0] = f2bf(a.x); p[1] = f2bf(a.y); p[2] = f2bf(a.z); p[3] = f2bf(a.w);
        *(ushort4v*)(nodes_bf + (long)wave * 256 + lane * 4) = p;
        const float4 w1 = *(const float4*)(ws_comb + lane * 4);
        const float4 w2 = *(const float4*)(wt_comb + lane * 4);
        float vs = a.x * w1.x + a.y * w1.y + a.z * w1.z + a.w * w1.w;
        float vt = a.x * w2.x + a.y * w2.y + a.z * w2.z + a.w * w2.w;
        #pragma unroll
        for (int off = 32; off; off >>= 1) {
          vs += __shfl_down(vs, off);
          vt += __shfl_down(vt, off);
        }
        if (lane == 0) { an_s[wave] = vs; an_t[wave] = vt; }
      }
    }
  }
  grid_barrier(bar, G);

  // ---- P3: GEMM tiles (both matrices) + alpha softmax chunks ----
  int maxM = Ms > Mt ? Ms : Mt;
  int ntx = (maxM + 127) / 128;
  int ntiles = ntx * 2 * 2;            // x * cols(2) * mats(2)
  int nalpha = (Ns * B2 + 255) / 256;
  for (int vt = bid; vt < ntiles + nalpha; vt += G) {
    if (vt >= ntiles) {
      int g = (vt - ntiles) * 256 + t;
      int s = g >> 1, b = g & 1;
      if (s < Ns) {
        float base = an_s[(long)usrc[s] * B2 + b] + consts[0] + consts[1] + ba[0];
        float ex[DEG];
        float den = 0.f;
        #pragma unroll
        for (int j = 0; j < DEG; ++j) {
          int tt = tid_arr[s * DEG + j];
          float sc = base + an_t[(long)utgt[tt] * B2 + b];
          sc = sc > 0.f ? sc : SLOPE * sc;
          sc = fminf(2.f, fmaxf(-2.f, sc));
          float ev = __expf(sc);
          ex[j] = ev;
          den += ev;
        }
        float inv = 1.f / den;
        #pragma unroll
        for (int j = 0; j < DEG; ++j) alpha[(long)(s * DEG + j) * B2 + b] = ex[j] * inv;
      }
      continue;
    }
    int second = vt / (ntx * 2);
    int rem = vt - second * ntx * 2;
    int cy = rem / ntx, cx = rem - cy * ntx;
    const int* idx = second ? utgt : usrc;
    const unsigned short* WT = second ? WvT : WsT;
    const float* bias = second ? bv : bs;
    int M = second ? Mt : Ms;
    int row0 = cx * 128, col0 = cy * 128;
    if (row0 >= M) continue;

    int srow = t >> 3;           // 0..31
    int scol = (t & 7) * 8;      // 0..56
    const unsigned short* ap[4];
    #pragma unroll
    for (int p = 0; p < 4; ++p) {
      int m = row0 + srow + 32 * p;
      int mc = m < M ? m : M - 1;
      long ar = (long)idx[mc >> 1] * B2 + (mc & 1);
      ap[p] = nodes_bf + ar * 256 + scol;
    }
    const unsigned short* bp[4];
    #pragma unroll
    for (int q = 0; q < 4; ++q)
      bp[q] = WT + (long)(col0 + srow + 32 * q) * 256 + scol;

    f32x4 acc[2][8];
    #pragma unroll
    for (int i = 0; i < 2; ++i)
      #pragma unroll
      for (int j = 0; j < 8; ++j) acc[i][j] = (f32x4)(0.f);

    for (int k0 = 0; k0 < 256; k0 += 64) {
      ushort8 av[4], bvv[4];
      #pragma unroll
      for (int p = 0; p < 4; ++p) av[p] = *(const ushort8*)(ap[p] + k0);
      #pragma unroll
      for (int q = 0; q < 4; ++q) bvv[q] = *(const ushort8*)(bp[q] + k0);
      __syncthreads();
      #pragma unroll
      for (int p = 0; p < 4; ++p)
        *(ushort8*)&As[(srow + 32 * p) * LDT + scol] = av[p];
      #pragma unroll
      for (int q = 0; q < 4; ++q)
        *(ushort8*)&Bs[(srow + 32 * q) * LDT + scol] = bvv[q];
      __syncthreads();
      #pragma unroll
      for (int ks = 0; ks < 64; ks += 32) {
        int ko = ks + (lane >> 4) * 8;
        short8 af0 = *(const short8*)&As[(32 * widx + (lane & 15)) * LDT + ko];
        short8 af1 = *(const short8*)&As[(32 * widx + 16 + (lane & 15)) * LDT + ko];
        #pragma unroll
        for (int j = 0; j < 8; ++j) {
          short8 bf = *(const short8*)&Bs[(16 * j + (lane & 15)) * LDT + ko];
          acc[0][j] = __builtin_amdgcn_mfma_f32_16x16x32_bf16(af0, bf, acc[0][j], 0, 0, 0);
          acc[1][j] = __builtin_amdgcn_mfma_f32_16x16x32_bf16(af1, bf, acc[1][j], 0, 0, 0);
        }
      }
    }
    int cq = lane >> 4;
    #pragma unroll
    for (int j = 0; j < 8; ++j) {
      int col = col0 + 16 * j + (lane & 15);
      float bval = bias[col];
      #pragma unroll
      for (int i = 0; i < 2; ++i) {
        #pragma unroll
        for (int r = 0; r < 4; ++r) {
          int row = row0 + 32 * widx + 16 * i + cq * 4 + r;
          if (row < M) {
            float v = acc[i][j][r] + bval;
            if (!second) out[(long)row * 256 + col] = v;
            else         vals_bf[(long)row * 256 + col] = f2bf(v);
          }
        }
      }
    }
  }
  grid_barrier(bar, G);

  // ---- P4: aggregate. One wave per source s covering both batch rows;
  // each gather is a contiguous 1 KB row-pair vals[t2*2+{0,1}][:]. ----
  int nb4 = (Ns + 3) / 4;
  for (int vb = bid; vb < nb4; vb += G) {
    int s = vb * 4 + widx;
    if (s >= Ns) continue;
    int f = tid_arr[s * DEG + (lane & 15)];   // edge id (reference quirk)
    int b = lane >> 5;
    float al = alpha[(long)f * B2 + b];
    int t2 = tid_arr[f];                      // value row = tid[tid[e]]
    float acc[8] = {0.f, 0.f, 0.f, 0.f, 0.f, 0.f, 0.f, 0.f};
    #pragma unroll
    for (int j = 0; j < DEG; ++j) {
      int rr = __shfl(t2, j);
      float aj = __shfl(al, (lane & 32) + j);  // b-matched alpha for edge j
      ushort8 v = *(const ushort8*)(vals_bf + (long)rr * 512 + lane * 8);
      #pragma unroll
      for (int k = 0; k < 8; ++k) acc[k] += aj * bf2f(v[k]);
    }
    long ob = (long)s * 512 + lane * 8;
    float4 p0 = *(const float4*)(out + ob);
    float4 p1 = *(const float4*)(out + ob + 4);
    p0.x += acc[0]; p0.y += acc[1]; p0.z += acc[2]; p0.w += acc[3];
    p1.x += acc[4]; p1.y += acc[5]; p1.z += acc[6]; p1.w += acc[7];
    *(float4*)(out + ob) = p0;
    *(float4*)(out + ob + 4) = p1;
  }
}

extern "C" void kernel_launch(void* const* d_in, const int* in_sizes, int n_in,
                              void* d_out, int out_size, void* d_ws, size_t ws_size,
                              hipStream_t stream) {
  const float* nodes = (const float*)d_in[0];
  const float* Ws = (const float*)d_in[1];
  const float* bs = (const float*)d_in[2];
  const float* Wt = (const float*)d_in[3];
  const float* bt = (const float*)d_in[4];
  const float* Wv = (const float*)d_in[5];
  const float* bv = (const float*)d_in[6];
  const float* Wa = (const float*)d_in[7];
  const float* ba = (const float*)d_in[8];
  const int* usrc = (const int*)d_in[9];
  const int* utgt = (const int*)d_in[10];
  const int* tidp = (const int*)d_in[12];
  int Ns = in_sizes[9], Nt = in_sizes[10];
  int NsB = Ns * B2, NtB = Nt * B2;
  long nrows = in_sizes[0] / 256;   // N_NODES * B2

  unsigned short* nodes_bf = (unsigned short*)d_ws;        // nrows*256
  unsigned short* WsT = nodes_bf + nrows * 256;            // 65536
  unsigned short* WvT = WsT + 65536;                       // 65536
  unsigned short* vals_bf = WvT + 65536;                   // NtB*256
  float* fbase = (float*)(vals_bf + (size_t)NtB * 256);
  float* an_s = fbase;                                     // nrows
  float* an_t = an_s + nrows;                              // nrows
  float* ws_comb = an_t + nrows;                           // 256
  float* wt_comb = ws_comb + 256;                          // 256
  float* consts = wt_comb + 256;                           // 2 (pad 16)
  float* alpha = consts + 16;                              // E*B2
  unsigned* bar = (unsigned*)(alpha + (size_t)Ns * DEG * B2 + 16);
  float* out = (float*)d_out;

  hipMemsetAsync(bar, 0, 2 * sizeof(unsigned), stream);
  fused_k<<<512, 256, 0, stream>>>(
      nodes, Ws, bs, Wt, bt, Wv, bv, Wa, ba, usrc, utgt, tidp,
      WsT, WvT, nodes_bf, ws_comb, wt_comb, consts, an_s, an_t,
      alpha, vals_bf, out, bar, (int)nrows, NsB, NtB, Ns);
}

// Round 8
// 133.334 us; speedup vs baseline: 2.9211x; 2.9211x over previous
//
#include <hip/hip_runtime.h>

#define B2 2
#define DEG 16
#define SLOPE 0.2f

typedef __attribute__((ext_vector_type(8))) short short8;
typedef __attribute__((ext_vector_type(8))) unsigned short ushort8;
typedef __attribute__((ext_vector_type(4))) unsigned short ushort4v;
typedef __attribute__((ext_vector_type(4))) float f32x4;

__device__ inline unsigned short f2bf(float f) {
  union { float f; unsigned u; } v; v.f = f;
  unsigned r = v.u + 0x7fff + ((v.u >> 16) & 1);   // RNE
  return (unsigned short)(r >> 16);
}
__device__ inline float bf2f(unsigned short u) {
  union { unsigned u; float f; } c; c.u = ((unsigned)u) << 16;
  return c.f;
}

__device__ inline float wave_dot256(const float* __restrict__ a,
                                    const float* __restrict__ b, int lane) {
  float4 x = *(const float4*)(a + lane * 4);
  float4 y = *(const float4*)(b + lane * 4);
  float v = x.x * y.x + x.y * y.y + x.z * y.z + x.w * y.w;
  #pragma unroll
  for (int off = 32; off; off >>= 1) v += __shfl_down(v, off);
  return v;
}

// D1: blocks 0..31 transpose Ws/Wv [K][N]f32 -> [N][K]bf16;
// blocks 32..160: ws_comb/wt_comb row-dots + consts.
// (Separate dispatch from D2: prep_nodes reads the combs — G16.)
__global__ __launch_bounds__(256) void prep_w_k(
    const float* __restrict__ Ws, const float* __restrict__ Wt,
    const float* __restrict__ Wv, const float* __restrict__ Wa,
    const float* __restrict__ bs, const float* __restrict__ bt,
    unsigned short* __restrict__ WsT, unsigned short* __restrict__ WvT,
    float* __restrict__ ws_comb, float* __restrict__ wt_comb,
    float* __restrict__ consts) {
  int bx = blockIdx.x;
  if (bx < 32) {
    const float* src = (bx & 16) ? Wv : Ws;
    unsigned short* dst = (bx & 16) ? WvT : WsT;
    int rc = bx & 15;
    int r0 = (rc >> 2) * 64, c0 = (rc & 3) * 64;
    __shared__ float tile[64][65];
    int tr = threadIdx.x >> 6, tc = threadIdx.x & 63;
    #pragma unroll
    for (int i = 0; i < 16; ++i) {
      int r = tr * 16 + i;
      tile[r][tc] = src[(long)(r0 + r) * 256 + c0 + tc];
    }
    __syncthreads();
    #pragma unroll
    for (int i = 0; i < 16; ++i) {
      int r = tr * 16 + i;
      dst[(long)(c0 + r) * 256 + r0 + tc] = f2bf(tile[tc][r]);
    }
  } else {
    int wave = (bx - 32) * 4 + (threadIdx.x >> 6);
    int lane = threadIdx.x & 63;
    if (wave >= 514) return;
    const float *vec, *wa;
    float* dst;
    if (wave < 256)       { vec = Ws + (long)wave * 256;         wa = Wa;       dst = ws_comb + wave; }
    else if (wave < 512)  { vec = Wt + (long)(wave - 256) * 256; wa = Wa + 256; dst = wt_comb + (wave - 256); }
    else if (wave == 512) { vec = bs; wa = Wa;       dst = consts; }
    else                  { vec = bt; wa = Wa + 256; dst = consts + 1; }
    float v = wave_dot256(vec, wa, lane);
    if (lane == 0) *dst = v;
  }
}

// D2: nodes f32->bf16 + per-row logits an_s/an_t. One wave per row.
__global__ __launch_bounds__(256) void prep_nodes_k(
    const float* __restrict__ nodes, const float* __restrict__ ws_comb,
    const float* __restrict__ wt_comb, unsigned short* __restrict__ nodes_bf,
    float* __restrict__ an_s, float* __restrict__ an_t, int nrows) {
  int wave = blockIdx.x * 4 + (threadIdx.x >> 6);
  int lane = threadIdx.x & 63;
  if (wave >= nrows) return;
  const float4 a = *(const float4*)(nodes + (long)wave * 256 + lane * 4);
  ushort4v p;
  p[0] = f2bf(a.x); p[1] = f2bf(a.y); p[2] = f2bf(a.z); p[3] = f2bf(a.w);
  *(ushort4v*)(nodes_bf + (long)wave * 256 + lane * 4) = p;
  const float4 w1 = *(const float4*)(ws_comb + lane * 4);
  const float4 w2 = *(const float4*)(wt_comb + lane * 4);
  float vs = a.x * w1.x + a.y * w1.y + a.z * w1.z + a.w * w1.w;
  float vt = a.x * w2.x + a.y * w2.y + a.z * w2.z + a.w * w2.w;
  #pragma unroll
  for (int off = 32; off; off >>= 1) {
    vs += __shfl_down(vs, off);
    vt += __shfl_down(vt, off);
  }
  if (lane == 0) { an_s[wave] = vs; an_t[wave] = vt; }
}

// D3: merged MFMA GEMM, 128x128 tile, BK=64, 4 waves x (32x128 per wave).
// z=0: src_proj->bf16 sproj_bf; z=1: vals->bf16; z=2 (y==0): alpha softmax
// (alpha reads only D2 outputs — safe fusion).
__global__ __launch_bounds__(256, 2) void gemm_mfma_k(
    const unsigned short* __restrict__ Abf,
    const int* __restrict__ usrc, const int* __restrict__ utgt,
    const unsigned short* __restrict__ WsT, const unsigned short* __restrict__ WvT,
    const float* __restrict__ bs, const float* __restrict__ bv,
    unsigned short* __restrict__ sproj_bf, unsigned short* __restrict__ vals_bf,
    const float* __restrict__ an_s, const float* __restrict__ an_t,
    const int* __restrict__ tid_arr, const float* __restrict__ consts,
    const float* __restrict__ ba, float* __restrict__ alpha,
    int Ms, int Mt, int Ns) {
  if (blockIdx.z == 2) {
    if (blockIdx.y != 0) return;
    int g = blockIdx.x * 256 + threadIdx.x;
    int s = g >> 1, b = g & 1;
    if (s >= Ns) return;
    float base = an_s[(long)usrc[s] * B2 + b] + consts[0] + consts[1] + ba[0];
    float ex[DEG];
    float den = 0.f;
    #pragma unroll
    for (int j = 0; j < DEG; ++j) {
      int t = tid_arr[s * DEG + j];
      float sc = base + an_t[(long)utgt[t] * B2 + b];
      sc = sc > 0.f ? sc : SLOPE * sc;
      sc = fminf(2.f, fmaxf(-2.f, sc));
      float ev = __expf(sc);
      ex[j] = ev;
      den += ev;
    }
    float inv = 1.f / den;
    #pragma unroll
    for (int j = 0; j < DEG; ++j) alpha[(long)(s * DEG + j) * B2 + b] = ex[j] * inv;
    return;
  }
  bool second = blockIdx.z != 0;
  const int* idx = second ? utgt : usrc;
  const unsigned short* WT = second ? WvT : WsT;
  const float* bias = second ? bv : bs;
  unsigned short* dstC = second ? vals_bf : sproj_bf;
  int M = second ? Mt : Ms;
  int row0 = blockIdx.x * 128, col0 = blockIdx.y * 128;
  if (row0 >= M) return;

  constexpr int LDT = 72;
  __shared__ unsigned short As[128 * LDT];
  __shared__ unsigned short Bs[128 * LDT];
  int t = threadIdx.x;
  int wv = t >> 6, lane = t & 63;
  int srow = t >> 3;           // 0..31
  int scol = (t & 7) * 8;      // 0..56
  const unsigned short* ap[4];
  #pragma unroll
  for (int p = 0; p < 4; ++p) {
    int m = row0 + srow + 32 * p;
    int mc = m < M ? m : M - 1;
    long ar = (long)idx[mc >> 1] * B2 + (mc & 1);
    ap[p] = Abf + ar * 256 + scol;
  }
  const unsigned short* bp[4];
  #pragma unroll
  for (int q = 0; q < 4; ++q)
    bp[q] = WT + (long)(col0 + srow + 32 * q) * 256 + scol;

  f32x4 acc[2][8];
  #pragma unroll
  for (int i = 0; i < 2; ++i)
    #pragma unroll
    for (int j = 0; j < 8; ++j) acc[i][j] = (f32x4)(0.f);

  for (int k0 = 0; k0 < 256; k0 += 64) {
    ushort8 av[4], bvv[4];
    #pragma unroll
    for (int p = 0; p < 4; ++p) av[p] = *(const ushort8*)(ap[p] + k0);
    #pragma unroll
    for (int q = 0; q < 4; ++q) bvv[q] = *(const ushort8*)(bp[q] + k0);
    __syncthreads();
    #pragma unroll
    for (int p = 0; p < 4; ++p)
      *(ushort8*)&As[(srow + 32 * p) * LDT + scol] = av[p];
    #pragma unroll
    for (int q = 0; q < 4; ++q)
      *(ushort8*)&Bs[(srow + 32 * q) * LDT + scol] = bvv[q];
    __syncthreads();
    #pragma unroll
    for (int ks = 0; ks < 64; ks += 32) {
      int ko = ks + (lane >> 4) * 8;
      short8 af0 = *(const short8*)&As[(32 * wv + (lane & 15)) * LDT + ko];
      short8 af1 = *(const short8*)&As[(32 * wv + 16 + (lane & 15)) * LDT + ko];
      #pragma unroll
      for (int j = 0; j < 8; ++j) {
        short8 bf = *(const short8*)&Bs[(16 * j + (lane & 15)) * LDT + ko];
        acc[0][j] = __builtin_amdgcn_mfma_f32_16x16x32_bf16(af0, bf, acc[0][j], 0, 0, 0);
        acc[1][j] = __builtin_amdgcn_mfma_f32_16x16x32_bf16(af1, bf, acc[1][j], 0, 0, 0);
      }
    }
  }
  int cq = lane >> 4;
  #pragma unroll
  for (int j = 0; j < 8; ++j) {
    int col = col0 + 16 * j + (lane & 15);
    float bval = bias[col];
    #pragma unroll
    for (int i = 0; i < 2; ++i) {
      #pragma unroll
      for (int r = 0; r < 4; ++r) {
        int row = row0 + 32 * wv + 16 * i + cq * 4 + r;
        if (row < M)
          dstC[(long)row * 256 + col] = f2bf(acc[i][j][r] + bval);
      }
    }
  }
}

// D4: ONE wave per source s covering both batch rows; pure store (no RMW):
// out[s,b,:] = sproj[s,b,:] + sum_j alpha[f_j,b] * vals[tid[f_j],b,:].
__global__ __launch_bounds__(256) void aggregate_k(
    const unsigned short* __restrict__ sproj, const unsigned short* __restrict__ vals,
    const float* __restrict__ alpha, const int* __restrict__ tid_arr,
    float* __restrict__ out, int Ns) {
  int s = blockIdx.x * 4 + (threadIdx.x >> 6);
  int lane = threadIdx.x & 63;
  if (s >= Ns) return;
  int f = tid_arr[s * DEG + (lane & 15)];   // edge id (reference quirk)
  int b = lane >> 5;
  float al = alpha[(long)f * B2 + b];       // alpha for (j=lane&15, b)
  int t2 = tid_arr[f];                      // value row = tid[tid[e]]
  ushort8 sp = *(const ushort8*)(sproj + (long)s * 512 + lane * 8);
  float acc[8];
  #pragma unroll
  for (int k = 0; k < 8; ++k) acc[k] = bf2f(sp[k]);
  #pragma unroll
  for (int j = 0; j < DEG; ++j) {
    int rr = __shfl(t2, j);
    float aj = __shfl(al, (lane & 32) + j);  // b-matched alpha for edge j
    ushort8 v = *(const ushort8*)(vals + (long)rr * 512 + lane * 8);
    #pragma unroll
    for (int k = 0; k < 8; ++k) acc[k] += aj * bf2f(v[k]);
  }
  long ob = (long)s * 512 + lane * 8;
  float4 p0, p1;
  p0.x = acc[0]; p0.y = acc[1]; p0.z = acc[2]; p0.w = acc[3];
  p1.x = acc[4]; p1.y = acc[5]; p1.z = acc[6]; p1.w = acc[7];
  *(float4*)(out + ob) = p0;
  *(float4*)(out + ob + 4) = p1;
}

extern "C" void kernel_launch(void* const* d_in, const int* in_sizes, int n_in,
                              void* d_out, int out_size, void* d_ws, size_t ws_size,
                              hipStream_t stream) {
  const float* nodes = (const float*)d_in[0];
  const float* Ws = (const float*)d_in[1];
  const float* bs = (const float*)d_in[2];
  const float* Wt = (const float*)d_in[3];
  const float* bt = (const float*)d_in[4];
  const float* Wv = (const float*)d_in[5];
  const float* bv = (const float*)d_in[6];
  const float* Wa = (const float*)d_in[7];
  const float* ba = (const float*)d_in[8];
  const int* usrc = (const int*)d_in[9];
  const int* utgt = (const int*)d_in[10];
  const int* tidp = (const int*)d_in[12];
  int Ns = in_sizes[9], Nt = in_sizes[10];
  int NsB = Ns * B2, NtB = Nt * B2;
  long nrows = in_sizes[0] / 256;   // N_NODES * B2

  unsigned short* nodes_bf = (unsigned short*)d_ws;        // nrows*256
  unsigned short* WsT = nodes_bf + nrows * 256;            // 65536
  unsigned short* WvT = WsT + 65536;                       // 65536
  unsigned short* vals_bf = WvT + 65536;                   // NtB*256
  unsigned short* sproj_bf = vals_bf + (size_t)NtB * 256;  // NsB*256
  float* fbase = (float*)(sproj_bf + (size_t)NsB * 256);
  float* an_s = fbase;                                     // nrows
  float* an_t = an_s + nrows;                              // nrows
  float* ws_comb = an_t + nrows;                           // 256
  float* wt_comb = ws_comb + 256;                          // 256
  float* consts = wt_comb + 256;                           // 2 (pad 16)
  float* alpha = consts + 16;                              // E*B2
  float* out = (float*)d_out;

  prep_w_k<<<161, 256, 0, stream>>>(Ws, Wt, Wv, Wa, bs, bt,
                                    WsT, WvT, ws_comb, wt_comb, consts);
  prep_nodes_k<<<(int)((nrows + 3) / 4), 256, 0, stream>>>(
      nodes, ws_comb, wt_comb, nodes_bf, an_s, an_t, (int)nrows);
  int maxM = NsB > NtB ? NsB : NtB;
  gemm_mfma_k<<<dim3((maxM + 127) / 128, 2, 3), 256, 0, stream>>>(
      nodes_bf, usrc, utgt, WsT, WvT, bs, bv, sproj_bf, vals_bf,
      an_s, an_t, tidp, consts, ba, alpha, NsB, NtB, Ns);
  aggregate_k<<<(Ns + 3) / 4, 256, 0, stream>>>(
      sproj_bf, vals_bf, alpha, tidp, out, Ns);
}